// Round 2
// baseline (4364.823 us; speedup 1.0000x reference)
//
#include <hip/hip_runtime.h>

#define Hn 1024
#define Bn 8
#define Ln 4096
#define DIn 2048

typedef __attribute__((ext_vector_type(8))) short short8;
typedef __attribute__((ext_vector_type(4))) short short4v;
typedef __attribute__((ext_vector_type(4))) float f32x4;

__device__ __forceinline__ float bf2f(short s) {
  return __uint_as_float(((unsigned)(unsigned short)s) << 16);
}
__device__ __forceinline__ short f2bf(float f) {
  unsigned u = __float_as_uint(f);
  u += 0x7fffu + ((u >> 16) & 1u);
  return (short)(u >> 16);
}
__device__ __forceinline__ float silu_f(float x) { return x / (1.f + __expf(-x)); }
__device__ __forceinline__ float softplus_f(float x) { return x > 20.f ? x : log1pf(__expf(x)); }

// ---------------- fp32 -> bf16 convert (x4 vectorized; n multiple of 1024) ----------------
__global__ __launch_bounds__(256) void f2bf4_kernel(const float* __restrict__ in,
                                                    short* __restrict__ out, int n4) {
  int i = blockIdx.x * 256 + threadIdx.x;
  if (i < n4) {
    f32x4 v = ((const f32x4*)in)[i];
    short4v o;
    o.x = f2bf(v.x); o.y = f2bf(v.y); o.z = f2bf(v.z); o.w = f2bf(v.w);
    ((short4v*)out)[i] = o;
  }
}

// ---------------- adaLN modulation: mod = silu(c) @ adaln_w.T + adaln_b ----------------
__global__ __launch_bounds__(256) void modcalc_kernel(const float* __restrict__ c,
    const float* __restrict__ aw, const float* __restrict__ ab, float* __restrict__ mod) {
  int wid = blockIdx.x * 4 + (threadIdx.x >> 6);
  int lane = threadIdx.x & 63;
  int b = wid / 3072, n = wid - b * 3072;
  const f32x4* cr = (const f32x4*)(c + b * Hn);
  const f32x4* wr = (const f32x4*)(aw + (size_t)n * Hn);
  float s = 0.f;
#pragma unroll
  for (int i = 0; i < 4; ++i) {
    f32x4 cv = cr[lane + 64 * i];
    f32x4 wv = wr[lane + 64 * i];
    s += silu_f(cv.x) * wv.x + silu_f(cv.y) * wv.y + silu_f(cv.z) * wv.z + silu_f(cv.w) * wv.w;
  }
#pragma unroll
  for (int m = 1; m < 64; m <<= 1) s += __shfl_xor(s, m, 64);
  if (lane == 0) mod[wid] = s + ab[n];
}

// ---------------- LayerNorm + modulate -> x1 (bf16); one wave per row ----------------
__global__ __launch_bounds__(256) void ln_mod_kernel(const float* __restrict__ x,
    const float* __restrict__ mod, short* __restrict__ x1, int b0) {
  int row = blockIdx.x * 4 + (threadIdx.x >> 6);
  int lane = threadIdx.x & 63;
  int b = b0 + (row >> 12);
  const f32x4* xr = (const f32x4*)(x + (size_t)row * Hn);
  f32x4 v[4];
  float s = 0.f, ss = 0.f;
#pragma unroll
  for (int i = 0; i < 4; ++i) {
    v[i] = xr[lane + 64 * i];
    s += v[i].x + v[i].y + v[i].z + v[i].w;
    ss += v[i].x * v[i].x + v[i].y * v[i].y + v[i].z * v[i].z + v[i].w * v[i].w;
  }
#pragma unroll
  for (int m = 1; m < 64; m <<= 1) {
    s += __shfl_xor(s, m, 64);
    ss += __shfl_xor(ss, m, 64);
  }
  float mu = s * (1.f / 1024.f);
  float var = ss * (1.f / 1024.f) - mu * mu;
  float r = rsqrtf(var + 1e-6f);
  const f32x4* shp = (const f32x4*)(mod + b * 3072);
  const f32x4* scp = (const f32x4*)(mod + b * 3072 + 1024);
#pragma unroll
  for (int i = 0; i < 4; ++i) {
    int k4 = lane + 64 * i;
    f32x4 sc = scp[k4], sh = shp[k4];
    short4v o;
    o.x = f2bf((v[i].x - mu) * r * (1.f + sc.x) + sh.x);
    o.y = f2bf((v[i].y - mu) * r * (1.f + sc.y) + sh.y);
    o.z = f2bf((v[i].z - mu) * r * (1.f + sc.z) + sh.z);
    o.w = f2bf((v[i].w - mu) * r * (1.f + sc.w) + sh.w);
    *(short4v*)&x1[(size_t)row * Hn + k4 * 4] = o;
  }
}

// ---------------- generic bf16 MFMA GEMM: out = A[M,K] @ W[N,K]^T (+epilogue) ----------------
// EPI: 0=bf16; 1=+bias bf16; 2=silu(+bias) bf16; 3=softplus(+bias) bf16;
//      4=silu(+bias)*mul bf16 (in-place on mul ok); 5=fp32;
//      6=final: out=xres+alpha*(acc+bias) fp32; 7=silu(acc)*mul bf16 (in-place on mul ok)
#define SA_STR 40
template <int EPI>
__global__ __launch_bounds__(256) void gemm_k(
    const short* __restrict__ A, const short* __restrict__ W,
    const float* __restrict__ bias, const short* mul,
    const float* __restrict__ xres, const float* __restrict__ modp,
    void* outp, int N, int K, int b0) {
  __shared__ short sA[128 * SA_STR];
  __shared__ short sB[128 * SA_STR];
  int tid = threadIdx.x;
  int wave = tid >> 6, lane = tid & 63;
  int bm0 = blockIdx.y * 128;
  int bn0 = blockIdx.x * 128;
  int wm = (wave >> 1) * 64, wn = (wave & 1) * 64;
  int lrow = lane & 15, kh = (lane >> 4) * 8;
  int srow = tid >> 2;
  int scol = (tid & 3) * 8;

  f32x4 acc[4][4];
#pragma unroll
  for (int i = 0; i < 4; i++)
#pragma unroll
    for (int j = 0; j < 4; j++) acc[i][j] = (f32x4)0.f;

  for (int k0 = 0; k0 < K; k0 += 32) {
#pragma unroll
    for (int p = 0; p < 2; ++p) {
      int r = srow + p * 64;
      short8 av = *(const short8*)&A[(size_t)(bm0 + r) * K + k0 + scol];
      *(short8*)&sA[r * SA_STR + scol] = av;
      int n = bn0 + r;
      short8 bv = (short8)0;
      if (n < N) bv = *(const short8*)&W[(size_t)n * K + k0 + scol];
      *(short8*)&sB[r * SA_STR + scol] = bv;
    }
    __syncthreads();
    short8 af[4], bfr[4];
#pragma unroll
    for (int i = 0; i < 4; i++) af[i] = *(const short8*)&sA[(wm + i * 16 + lrow) * SA_STR + kh];
#pragma unroll
    for (int j = 0; j < 4; j++) bfr[j] = *(const short8*)&sB[(wn + j * 16 + lrow) * SA_STR + kh];
#pragma unroll
    for (int i = 0; i < 4; i++)
#pragma unroll
      for (int j = 0; j < 4; j++)
        acc[i][j] = __builtin_amdgcn_mfma_f32_16x16x32_bf16(af[i], bfr[j], acc[i][j], 0, 0, 0);
    __syncthreads();
  }

  int orow4 = (lane >> 4) * 4;
  int ocol = lane & 15;
#pragma unroll
  for (int i = 0; i < 4; i++)
#pragma unroll
    for (int j = 0; j < 4; j++)
#pragma unroll
      for (int r = 0; r < 4; r++) {
        int row = bm0 + wm + i * 16 + orow4 + r;
        int col = bn0 + wn + j * 16 + ocol;
        if (col >= N) continue;
        float v = acc[i][j][r];
        size_t idx = (size_t)row * N + col;
        if (EPI == 0) {
          ((short*)outp)[idx] = f2bf(v);
        } else if (EPI == 1) {
          ((short*)outp)[idx] = f2bf(v + bias[col]);
        } else if (EPI == 2) {
          ((short*)outp)[idx] = f2bf(silu_f(v + bias[col]));
        } else if (EPI == 3) {
          ((short*)outp)[idx] = f2bf(softplus_f(v + bias[col]));
        } else if (EPI == 4) {
          float t = silu_f(v + bias[col]) * bf2f(mul[idx]);
          ((short*)outp)[idx] = f2bf(t);
        } else if (EPI == 5) {
          ((float*)outp)[idx] = v;
        } else if (EPI == 6) {
          int b = b0 + (row >> 12);
          float t = v + bias[col];
          ((float*)outp)[idx] = xres[idx] + modp[b * 3072 + 2048 + col] * t;
        } else if (EPI == 7) {
          float t = silu_f(v) * bf2f(mul[idx]);
          ((short*)outp)[idx] = f2bf(t);
        }
      }
}

// ---------------- causal depthwise conv (DC=4) + SiLU ----------------
__global__ __launch_bounds__(256) void conv_kernel(const short* __restrict__ xm,
    const float* __restrict__ cw, const float* __restrict__ cb, short* __restrict__ xc) {
  size_t idx = (size_t)blockIdx.x * 256 + threadIdx.x;
  int d = (int)(idx & (DIn - 1));
  size_t bt = idx >> 11;
  int t = (int)(bt & (Ln - 1));
  f32x4 w = *(const f32x4*)(cw + d * 4);
  float wj[4] = {w.x, w.y, w.z, w.w};
  float acc = cb[d];
#pragma unroll
  for (int j = 0; j < 4; ++j) {
    int tt = t - 3 + j;
    if (tt >= 0) acc += bf2f(xm[(bt - 3 + j) * DIn + d]) * wj[j];
  }
  xc[idx] = f2bf(silu_f(acc));
}

// ---------------- slice dbl[:, :64] -> bf16 ----------------
__global__ __launch_bounds__(256) void dtslice_kernel(const float* __restrict__ dbl,
                                                      short* __restrict__ dtb) {
  int idx = blockIdx.x * 256 + threadIdx.x;
  int row = idx >> 6, col = idx & 63;
  dtb[idx] = f2bf(dbl[(size_t)row * 96 + col]);
}

// ---------------- selective scan: y_raw = scan + xc*D  (gating applied later) ----------------
// one thread per (b,d). NOTE: dt and y may ALIAS (same buffer) — no __restrict__ on them.
// Safe because at step t we read row t+1 before writing row t, per-thread-owned column.
__global__ __launch_bounds__(64) void scan_kernel(const short* dt,
    const short* __restrict__ xc, const float* __restrict__ dbl,
    const float* __restrict__ A_log, const float* __restrict__ Dv, short* y) {
  int b = blockIdx.x >> 5;
  int d = ((blockIdx.x & 31) << 6) + threadIdx.x;
  float A[16], h[16];
#pragma unroll
  for (int s = 0; s < 16; ++s) {
    A[s] = -__expf(A_log[d * 16 + s]);
    h[s] = 0.f;
  }
  float Dd = Dv[d];
  size_t rb = (size_t)b * Ln;
  float dtv = bf2f(dt[rb * DIn + d]);
  float xv = bf2f(xc[rb * DIn + d]);
  float bc[32];
  {
    const f32x4* p = (const f32x4*)(dbl + rb * 96 + 64);
#pragma unroll
    for (int i = 0; i < 8; ++i) {
      f32x4 q = p[i];
      bc[4 * i] = q.x; bc[4 * i + 1] = q.y; bc[4 * i + 2] = q.z; bc[4 * i + 3] = q.w;
    }
  }
  for (int t = 0; t < Ln; ++t) {
    int tn = (t + 1 < Ln) ? t + 1 : t;
    size_t rn = rb + tn;
    float dtv2 = bf2f(dt[rn * DIn + d]);
    float xv2 = bf2f(xc[rn * DIn + d]);
    float bc2[32];
    {
      const f32x4* p = (const f32x4*)(dbl + rn * 96 + 64);
#pragma unroll
      for (int i = 0; i < 8; ++i) {
        f32x4 q = p[i];
        bc2[4 * i] = q.x; bc2[4 * i + 1] = q.y; bc2[4 * i + 2] = q.z; bc2[4 * i + 3] = q.w;
      }
    }
    float u = dtv * xv;
    float acc = 0.f;
#pragma unroll
    for (int s = 0; s < 16; ++s) {
      float e = __expf(dtv * A[s]);
      h[s] = h[s] * e + u * bc[s];
      acc += h[s] * bc[16 + s];
    }
    y[(rb + t) * DIn + d] = f2bf(acc + xv * Dd);
    dtv = dtv2; xv = xv2;
#pragma unroll
    for (int i = 0; i < 32; ++i) bc[i] = bc2[i];
  }
}

extern "C" void kernel_launch(void* const* d_in, const int* in_sizes, int n_in,
                              void* d_out, int out_size, void* d_ws, size_t ws_size,
                              hipStream_t stream) {
  const float* x = (const float*)d_in[0];
  const float* c = (const float*)d_in[1];
  const float* adaln_w = (const float*)d_in[2];
  const float* adaln_b = (const float*)d_in[3];
  const float* hgd_w1 = (const float*)d_in[4];
  const float* hgd_b1 = (const float*)d_in[5];
  const float* hgd_w2 = (const float*)d_in[6];
  const float* hgd_b2 = (const float*)d_in[7];
  const float* hgf_wm = (const float*)d_in[8];
  const float* hgf_bm = (const float*)d_in[9];
  const float* hgf_wr = (const float*)d_in[10];
  const float* hgf_br = (const float*)d_in[11];
  const float* hgf_wf = (const float*)d_in[12];
  const float* hgf_bf = (const float*)d_in[13];
  const float* in_w = (const float*)d_in[14];
  const float* conv_w = (const float*)d_in[15];
  const float* conv_b = (const float*)d_in[16];
  const float* xproj_w = (const float*)d_in[17];
  const float* dtproj_w = (const float*)d_in[18];
  const float* dt_bias = (const float*)d_in[19];
  const float* A_log = (const float*)d_in[20];
  const float* Dv = (const float*)d_in[21];
  const float* out_w = (const float*)d_in[22];
  (void)in_sizes; (void)n_in; (void)out_size;

  // ---- persistent region: bf16 weights + modulation ----
  char* ws = (char*)d_ws;
  size_t off = 0;
  auto alloc = [&](size_t bytes) -> void* {
    void* p = ws + off;
    off += (bytes + 255) & ~(size_t)255;
    return p;
  };
  short* w1b = (short*)alloc((size_t)256 * 1024 * 2);
  short* w2b = (short*)alloc((size_t)1024 * 256 * 2);
  short* wmb = (short*)alloc((size_t)256 * 1024 * 2);
  short* wrb = (short*)alloc((size_t)256 * 1024 * 2);
  short* wfb = (short*)alloc((size_t)1024 * 256 * 2);
  short* inwb = (short*)alloc((size_t)4096 * 1024 * 2);
  short* xpb = (short*)alloc((size_t)96 * 2048 * 2);
  short* dtpb = (short*)alloc((size_t)2048 * 64 * 2);
  short* owb = (short*)alloc((size_t)1024 * 2048 * 2);
  float* modb = (float*)alloc((size_t)Bn * 3072 * 4);
  size_t persist = off;

  // ---- pick batch-chunking so workspace fits: per-chunk bytes = Mc*12800 ----
  int BC = 8;
  while (BC > 1 && persist + (size_t)BC * Ln * 12800 > ws_size) BC >>= 1;
  int nchunk = 8 / BC;
  size_t Mc = (size_t)BC * Ln;

  short* x1 = (short*)alloc(Mc * 1024 * 2);
  short* hd = (short*)alloc(Mc * 1024 * 2);
  short* xm = (short*)alloc(Mc * 2048 * 2);   // in_proj x -> (conv) -> dt -> y_raw -> y
  short* xct = (short*)alloc(Mc * 2048 * 2);  // conv out; t1 (Mc*256) aliases here later
  float* dbl = (float*)alloc(Mc * 96 * 4);
  short* dtb = (short*)alloc(Mc * 64 * 2);
  short* t1 = xct;  // alias: hourglass 256-wide intermediates (disjoint lifetime vs conv out)

  auto conv1 = [&](const float* src, short* dst, int n) {
    f2bf4_kernel<<<(n / 4 + 255) / 256, 256, 0, stream>>>(src, dst, n / 4);
  };
  conv1(hgd_w1, w1b, 256 * 1024);
  conv1(hgd_w2, w2b, 1024 * 256);
  conv1(hgf_wm, wmb, 256 * 1024);
  conv1(hgf_wr, wrb, 256 * 1024);
  conv1(hgf_wf, wfb, 1024 * 256);
  conv1(in_w, inwb, 4096 * 1024);
  conv1(xproj_w, xpb, 96 * 2048);
  conv1(dtproj_w, dtpb, 2048 * 64);
  conv1(out_w, owb, 1024 * 2048);

  modcalc_kernel<<<(Bn * 3072) / 4, 256, 0, stream>>>(c, adaln_w, adaln_b, modb);

  dim3 blk(256);
  int gy = (int)(Mc / 128);
  for (int ck = 0; ck < nchunk; ++ck) {
    int b0 = ck * BC;
    const float* xch = x + (size_t)b0 * Ln * Hn;
    float* och = (float*)d_out + (size_t)b0 * Ln * Hn;

    // LN + modulate
    ln_mod_kernel<<<(int)(Mc / 4), blk, 0, stream>>>(xch, modb, x1, b0);
    // hourglass dense: x1 -> t1 -> hd
    gemm_k<2><<<dim3(2, gy), blk, 0, stream>>>(x1, w1b, hgd_b1, nullptr, nullptr, nullptr, t1, 256, 1024, 0);
    gemm_k<1><<<dim3(8, gy), blk, 0, stream>>>(t1, w2b, hgd_b2, nullptr, nullptr, nullptr, hd, 1024, 256, 0);
    // in_proj (x half only) -> xm
    gemm_k<0><<<dim3(16, gy), blk, 0, stream>>>(hd, inwb, nullptr, nullptr, nullptr, nullptr, xm, 2048, 1024, 0);
    // causal conv + silu: xm -> xct
    conv_kernel<<<(int)(Mc * 2048 / 256), blk, 0, stream>>>(xm, conv_w, conv_b, xct);
    // x-proj (fp32 out): xct -> dbl
    gemm_k<5><<<dim3(1, gy), blk, 0, stream>>>(xct, xpb, nullptr, nullptr, nullptr, nullptr, dbl, 96, 2048, 0);
    // dt slice + dt-proj (softplus): -> xm (aliases dead in_proj x)
    dtslice_kernel<<<(int)(Mc * 64 / 256), blk, 0, stream>>>(dbl, dtb);
    gemm_k<3><<<dim3(16, gy), blk, 0, stream>>>(dtb, dtpb, dt_bias, nullptr, nullptr, nullptr, xm, 2048, 64, 0);
    // selective scan: dt(xm), xc(xct), B/C(dbl) -> y_raw (in place in xm)
    scan_kernel<<<BC * 32, 64, 0, stream>>>(xm, xct, dbl, A_log, Dv, xm);
    // gating GEMM: y = silu(hd @ in_w_zhalf^T) * y_raw  (in place in xm)
    gemm_k<7><<<dim3(16, gy), blk, 0, stream>>>(hd, inwb + (size_t)2048 * 1024, nullptr, xm, nullptr, nullptr, xm, 2048, 1024, 0);
    // out_proj: xm -> hd (x1_2)
    gemm_k<0><<<dim3(8, gy), blk, 0, stream>>>(xm, owb, nullptr, nullptr, nullptr, nullptr, hd, 1024, 2048, 0);
    // hourglass fusion
    gemm_k<2><<<dim3(2, gy), blk, 0, stream>>>(hd, wmb, hgf_bm, nullptr, nullptr, nullptr, t1, 256, 1024, 0);
    gemm_k<4><<<dim3(2, gy), blk, 0, stream>>>(x1, wrb, hgf_br, t1, nullptr, nullptr, t1, 256, 1024, 0);
    gemm_k<6><<<dim3(8, gy), blk, 0, stream>>>(t1, wfb, hgf_bf, nullptr, xch, modb, och, 1024, 256, b0);
  }
}

// Round 3
// 2659.734 us; speedup vs baseline: 1.6411x; 1.6411x over previous
//
#include <hip/hip_runtime.h>

#define Hn 1024
#define Bn 8
#define Ln 4096
#define DIn 2048
#define NCH 64
#define CLn 64   // Ln / NCH

typedef __attribute__((ext_vector_type(8))) short short8;
typedef __attribute__((ext_vector_type(4))) short short4v;
typedef __attribute__((ext_vector_type(4))) float f32x4;

__device__ __forceinline__ float bf2f(short s) {
  return __uint_as_float(((unsigned)(unsigned short)s) << 16);
}
__device__ __forceinline__ short f2bf(float f) {
  unsigned u = __float_as_uint(f);
  u += 0x7fffu + ((u >> 16) & 1u);
  return (short)(u >> 16);
}
__device__ __forceinline__ float silu_f(float x) { return x / (1.f + __expf(-x)); }
__device__ __forceinline__ float softplus_f(float x) { return x > 20.f ? x : log1pf(__expf(x)); }

// ---------------- fp32 -> bf16 convert (x4 vectorized) ----------------
__global__ __launch_bounds__(256) void f2bf4_kernel(const float* __restrict__ in,
                                                    short* __restrict__ out, int n4) {
  int i = blockIdx.x * 256 + threadIdx.x;
  if (i < n4) {
    f32x4 v = ((const f32x4*)in)[i];
    short4v o;
    o.x = f2bf(v.x); o.y = f2bf(v.y); o.z = f2bf(v.z); o.w = f2bf(v.w);
    ((short4v*)out)[i] = o;
  }
}

// ---------------- adaLN modulation ----------------
__global__ __launch_bounds__(256) void modcalc_kernel(const float* __restrict__ c,
    const float* __restrict__ aw, const float* __restrict__ ab, float* __restrict__ mod) {
  int wid = blockIdx.x * 4 + (threadIdx.x >> 6);
  int lane = threadIdx.x & 63;
  int b = wid / 3072, n = wid - b * 3072;
  const f32x4* cr = (const f32x4*)(c + b * Hn);
  const f32x4* wr = (const f32x4*)(aw + (size_t)n * Hn);
  float s = 0.f;
#pragma unroll
  for (int i = 0; i < 4; ++i) {
    f32x4 cv = cr[lane + 64 * i];
    f32x4 wv = wr[lane + 64 * i];
    s += silu_f(cv.x) * wv.x + silu_f(cv.y) * wv.y + silu_f(cv.z) * wv.z + silu_f(cv.w) * wv.w;
  }
#pragma unroll
  for (int m = 1; m < 64; m <<= 1) s += __shfl_xor(s, m, 64);
  if (lane == 0) mod[wid] = s + ab[n];
}

// ---------------- LayerNorm + modulate -> x1 (bf16) ----------------
__global__ __launch_bounds__(256) void ln_mod_kernel(const float* __restrict__ x,
    const float* __restrict__ mod, short* __restrict__ x1, int b0) {
  int row = blockIdx.x * 4 + (threadIdx.x >> 6);
  int lane = threadIdx.x & 63;
  int b = b0 + (row >> 12);
  const f32x4* xr = (const f32x4*)(x + (size_t)row * Hn);
  f32x4 v[4];
  float s = 0.f, ss = 0.f;
#pragma unroll
  for (int i = 0; i < 4; ++i) {
    v[i] = xr[lane + 64 * i];
    s += v[i].x + v[i].y + v[i].z + v[i].w;
    ss += v[i].x * v[i].x + v[i].y * v[i].y + v[i].z * v[i].z + v[i].w * v[i].w;
  }
#pragma unroll
  for (int m = 1; m < 64; m <<= 1) {
    s += __shfl_xor(s, m, 64);
    ss += __shfl_xor(ss, m, 64);
  }
  float mu = s * (1.f / 1024.f);
  float var = ss * (1.f / 1024.f) - mu * mu;
  float r = rsqrtf(var + 1e-6f);
  const f32x4* shp = (const f32x4*)(mod + b * 3072);
  const f32x4* scp = (const f32x4*)(mod + b * 3072 + 1024);
#pragma unroll
  for (int i = 0; i < 4; ++i) {
    int k4 = lane + 64 * i;
    f32x4 sc = scp[k4], sh = shp[k4];
    short4v o;
    o.x = f2bf((v[i].x - mu) * r * (1.f + sc.x) + sh.x);
    o.y = f2bf((v[i].y - mu) * r * (1.f + sc.y) + sh.y);
    o.z = f2bf((v[i].z - mu) * r * (1.f + sc.z) + sh.z);
    o.w = f2bf((v[i].w - mu) * r * (1.f + sc.w) + sh.w);
    *(short4v*)&x1[(size_t)row * Hn + k4 * 4] = o;
  }
}

// ---------------- generic bf16 MFMA GEMM: out = A[M,K] @ W[N,K]^T (+epilogue) ----------------
#define SA_STR 40
template <int EPI>
__global__ __launch_bounds__(256) void gemm_k(
    const short* __restrict__ A, const short* __restrict__ W,
    const float* __restrict__ bias, const short* mul,
    const float* __restrict__ xres, const float* __restrict__ modp,
    void* outp, int N, int K, int b0) {
  __shared__ short sA[128 * SA_STR];
  __shared__ short sB[128 * SA_STR];
  int tid = threadIdx.x;
  int wave = tid >> 6, lane = tid & 63;
  int bm0 = blockIdx.y * 128;
  int bn0 = blockIdx.x * 128;
  int wm = (wave >> 1) * 64, wn = (wave & 1) * 64;
  int lrow = lane & 15, kh = (lane >> 4) * 8;
  int srow = tid >> 2;
  int scol = (tid & 3) * 8;

  f32x4 acc[4][4];
#pragma unroll
  for (int i = 0; i < 4; i++)
#pragma unroll
    for (int j = 0; j < 4; j++) acc[i][j] = (f32x4)0.f;

  for (int k0 = 0; k0 < K; k0 += 32) {
#pragma unroll
    for (int p = 0; p < 2; ++p) {
      int r = srow + p * 64;
      short8 av = *(const short8*)&A[(size_t)(bm0 + r) * K + k0 + scol];
      *(short8*)&sA[r * SA_STR + scol] = av;
      int n = bn0 + r;
      short8 bv = (short8)0;
      if (n < N) bv = *(const short8*)&W[(size_t)n * K + k0 + scol];
      *(short8*)&sB[r * SA_STR + scol] = bv;
    }
    __syncthreads();
    short8 af[4], bfr[4];
#pragma unroll
    for (int i = 0; i < 4; i++) af[i] = *(const short8*)&sA[(wm + i * 16 + lrow) * SA_STR + kh];
#pragma unroll
    for (int j = 0; j < 4; j++) bfr[j] = *(const short8*)&sB[(wn + j * 16 + lrow) * SA_STR + kh];
#pragma unroll
    for (int i = 0; i < 4; i++)
#pragma unroll
      for (int j = 0; j < 4; j++)
        acc[i][j] = __builtin_amdgcn_mfma_f32_16x16x32_bf16(af[i], bfr[j], acc[i][j], 0, 0, 0);
    __syncthreads();
  }

  int orow4 = (lane >> 4) * 4;
  int ocol = lane & 15;
#pragma unroll
  for (int i = 0; i < 4; i++)
#pragma unroll
    for (int j = 0; j < 4; j++)
#pragma unroll
      for (int r = 0; r < 4; r++) {
        int row = bm0 + wm + i * 16 + orow4 + r;
        int col = bn0 + wn + j * 16 + ocol;
        if (col >= N) continue;
        float v = acc[i][j][r];
        size_t idx = (size_t)row * N + col;
        if (EPI == 0) {
          ((short*)outp)[idx] = f2bf(v);
        } else if (EPI == 1) {
          ((short*)outp)[idx] = f2bf(v + bias[col]);
        } else if (EPI == 2) {
          ((short*)outp)[idx] = f2bf(silu_f(v + bias[col]));
        } else if (EPI == 3) {
          ((short*)outp)[idx] = f2bf(softplus_f(v + bias[col]));
        } else if (EPI == 4) {
          float t = silu_f(v + bias[col]) * bf2f(mul[idx]);
          ((short*)outp)[idx] = f2bf(t);
        } else if (EPI == 5) {
          ((float*)outp)[idx] = v;
        } else if (EPI == 6) {
          int b = b0 + (row >> 12);
          float t = v + bias[col];
          ((float*)outp)[idx] = xres[idx] + modp[b * 3072 + 2048 + col] * t;
        } else if (EPI == 7) {
          float t = silu_f(v) * bf2f(mul[idx]);
          ((short*)outp)[idx] = f2bf(t);
        }
      }
}

// ---------------- causal depthwise conv (DC=4) + SiLU ----------------
__global__ __launch_bounds__(256) void conv_kernel(const short* __restrict__ xm,
    const float* __restrict__ cw, const float* __restrict__ cb, short* __restrict__ xc) {
  size_t idx = (size_t)blockIdx.x * 256 + threadIdx.x;
  int d = (int)(idx & (DIn - 1));
  size_t bt = idx >> 11;
  int t = (int)(bt & (Ln - 1));
  f32x4 w = *(const f32x4*)(cw + d * 4);
  float wj[4] = {w.x, w.y, w.z, w.w};
  float acc = cb[d];
#pragma unroll
  for (int j = 0; j < 4; ++j) {
    int tt = t - 3 + j;
    if (tt >= 0) acc += bf2f(xm[(bt - 3 + j) * DIn + d]) * wj[j];
  }
  xc[idx] = f2bf(silu_f(acc));
}

// ---------------- slice dbl[:, :64] -> bf16 ----------------
__global__ __launch_bounds__(256) void dtslice_kernel(const float* __restrict__ dbl,
                                                      short* __restrict__ dtb) {
  int idx = blockIdx.x * 256 + threadIdx.x;
  int row = idx >> 6, col = idx & 63;
  dtb[idx] = f2bf(dbl[(size_t)row * 96 + col]);
}

// ================= chunked parallel selective scan =================
// thread g -> d = g&2047, c = (g>>11)&63, b = g>>17 (within chunk-batch BC)
// pass 1: local scan from h=0 over CLn steps; store h_end[16] + sum(dt)
__global__ __launch_bounds__(256) void scan_part1(const short* __restrict__ dt,
    const short* __restrict__ xc, const float* __restrict__ dbl,
    const float* __restrict__ A_log, float* __restrict__ hq, float* __restrict__ sd) {
  int g = blockIdx.x * 256 + threadIdx.x;
  int d = g & (DIn - 1);
  int r = g >> 11;
  int c = r & (NCH - 1);
  int b = r >> 6;
  float A[16], h[16];
#pragma unroll
  for (int s = 0; s < 16; ++s) {
    A[s] = -__expf(A_log[d * 16 + s]);
    h[s] = 0.f;
  }
  float sum = 0.f;
  size_t rb = (size_t)b * Ln + (size_t)c * CLn;
  for (int t = 0; t < CLn; ++t) {
    size_t row = rb + t;
    float dtv = bf2f(dt[row * DIn + d]);
    float xv = bf2f(xc[row * DIn + d]);
    const f32x4* p = (const f32x4*)(dbl + row * 96 + 64);
    float Bv[16];
#pragma unroll
    for (int i = 0; i < 4; ++i) {
      f32x4 q = p[i];
      Bv[4 * i] = q.x; Bv[4 * i + 1] = q.y; Bv[4 * i + 2] = q.z; Bv[4 * i + 3] = q.w;
    }
    float u = dtv * xv;
    sum += dtv;
#pragma unroll
    for (int s = 0; s < 16; ++s) h[s] = h[s] * __expf(dtv * A[s]) + u * Bv[s];
  }
  size_t bd = (size_t)b * DIn + d;
  f32x4* out = (f32x4*)(hq + (bd * NCH + c) * 16);
#pragma unroll
  for (int i = 0; i < 4; ++i) {
    f32x4 o; o.x = h[4 * i]; o.y = h[4 * i + 1]; o.z = h[4 * i + 2]; o.w = h[4 * i + 3];
    out[i] = o;
  }
  sd[bd * NCH + c] = sum;
}

// pass combine: thread per (b,d,s); sequential over chunks; hq becomes h_start
__global__ __launch_bounds__(256) void scan_combine(const float* __restrict__ A_log,
    const float* __restrict__ sd, float* hq) {
  int g = blockIdx.x * 256 + threadIdx.x;
  int s = g & 15;
  size_t bd = (size_t)(g >> 4);
  int d = (int)(bd & (DIn - 1));
  float A = -__expf(A_log[d * 16 + s]);
  float H = 0.f;
  for (int c = 0; c < NCH; ++c) {
    size_t idx = (bd * NCH + c) * 16 + s;
    float he = hq[idx];
    float e = __expf(A * sd[bd * NCH + c]);
    hq[idx] = H;
    H = H * e + he;
  }
}

// pass 2: local scan seeded with h_start; y = h·C + xc*D. dt/y may alias (read-t-then-write-t).
__global__ __launch_bounds__(256) void scan_part2(const short* dt,
    const short* __restrict__ xc, const float* __restrict__ dbl,
    const float* __restrict__ A_log, const float* __restrict__ Dv,
    const float* __restrict__ hq, short* y) {
  int g = blockIdx.x * 256 + threadIdx.x;
  int d = g & (DIn - 1);
  int r = g >> 11;
  int c = r & (NCH - 1);
  int b = r >> 6;
  size_t bd = (size_t)b * DIn + d;
  float A[16], h[16];
#pragma unroll
  for (int s = 0; s < 16; ++s) A[s] = -__expf(A_log[d * 16 + s]);
  const f32x4* hin = (const f32x4*)(hq + (bd * NCH + c) * 16);
#pragma unroll
  for (int i = 0; i < 4; ++i) {
    f32x4 q = hin[i];
    h[4 * i] = q.x; h[4 * i + 1] = q.y; h[4 * i + 2] = q.z; h[4 * i + 3] = q.w;
  }
  float Dd = Dv[d];
  size_t rb = (size_t)b * Ln + (size_t)c * CLn;
  for (int t = 0; t < CLn; ++t) {
    size_t row = rb + t;
    float dtv = bf2f(dt[row * DIn + d]);
    float xv = bf2f(xc[row * DIn + d]);
    const f32x4* p = (const f32x4*)(dbl + row * 96 + 64);
    float bc[32];
#pragma unroll
    for (int i = 0; i < 8; ++i) {
      f32x4 q = p[i];
      bc[4 * i] = q.x; bc[4 * i + 1] = q.y; bc[4 * i + 2] = q.z; bc[4 * i + 3] = q.w;
    }
    float u = dtv * xv;
    float acc = 0.f;
#pragma unroll
    for (int s = 0; s < 16; ++s) {
      h[s] = h[s] * __expf(dtv * A[s]) + u * bc[s];
      acc += h[s] * bc[16 + s];
    }
    y[row * DIn + d] = f2bf(acc + xv * Dd);
  }
}

extern "C" void kernel_launch(void* const* d_in, const int* in_sizes, int n_in,
                              void* d_out, int out_size, void* d_ws, size_t ws_size,
                              hipStream_t stream) {
  const float* x = (const float*)d_in[0];
  const float* c = (const float*)d_in[1];
  const float* adaln_w = (const float*)d_in[2];
  const float* adaln_b = (const float*)d_in[3];
  const float* hgd_w1 = (const float*)d_in[4];
  const float* hgd_b1 = (const float*)d_in[5];
  const float* hgd_w2 = (const float*)d_in[6];
  const float* hgd_b2 = (const float*)d_in[7];
  const float* hgf_wm = (const float*)d_in[8];
  const float* hgf_bm = (const float*)d_in[9];
  const float* hgf_wr = (const float*)d_in[10];
  const float* hgf_br = (const float*)d_in[11];
  const float* hgf_wf = (const float*)d_in[12];
  const float* hgf_bf = (const float*)d_in[13];
  const float* in_w = (const float*)d_in[14];
  const float* conv_w = (const float*)d_in[15];
  const float* conv_b = (const float*)d_in[16];
  const float* xproj_w = (const float*)d_in[17];
  const float* dtproj_w = (const float*)d_in[18];
  const float* dt_bias = (const float*)d_in[19];
  const float* A_log = (const float*)d_in[20];
  const float* Dv = (const float*)d_in[21];
  const float* out_w = (const float*)d_in[22];
  (void)in_sizes; (void)n_in; (void)out_size;

  // ---- persistent region: bf16 weights + modulation ----
  char* ws = (char*)d_ws;
  size_t off = 0;
  auto alloc = [&](size_t bytes) -> void* {
    void* p = ws + off;
    off += (bytes + 255) & ~(size_t)255;
    return p;
  };
  short* w1b = (short*)alloc((size_t)256 * 1024 * 2);
  short* w2b = (short*)alloc((size_t)1024 * 256 * 2);
  short* wmb = (short*)alloc((size_t)256 * 1024 * 2);
  short* wrb = (short*)alloc((size_t)256 * 1024 * 2);
  short* wfb = (short*)alloc((size_t)1024 * 256 * 2);
  short* inwb = (short*)alloc((size_t)4096 * 1024 * 2);
  short* xpb = (short*)alloc((size_t)96 * 2048 * 2);
  short* dtpb = (short*)alloc((size_t)2048 * 64 * 2);
  short* owb = (short*)alloc((size_t)1024 * 2048 * 2);
  float* modb = (float*)alloc((size_t)Bn * 3072 * 4);
  size_t persist = off;

  // ---- batch-chunking: per-chunk bytes = Mc*14976 (incl. hq/sd) ----
  int BC = 8;
  while (BC > 1 && persist + (size_t)BC * Ln * 14976 > ws_size) BC >>= 1;
  int nchunk = 8 / BC;
  size_t Mc = (size_t)BC * Ln;

  short* x1 = (short*)alloc(Mc * 1024 * 2);
  short* hd = (short*)alloc(Mc * 1024 * 2);
  short* xm = (short*)alloc(Mc * 2048 * 2);   // in_proj x -> dt -> y_raw -> y
  short* xct = (short*)alloc(Mc * 2048 * 2);  // conv out; t1 aliases
  float* dbl = (float*)alloc(Mc * 96 * 4);
  short* dtb = (short*)alloc(Mc * 64 * 2);
  float* hq = (float*)alloc((size_t)BC * DIn * NCH * 16 * 4);
  float* sd = (float*)alloc((size_t)BC * DIn * NCH * 4);
  short* t1 = xct;

  auto conv1 = [&](const float* src, short* dst, int n) {
    f2bf4_kernel<<<(n / 4 + 255) / 256, 256, 0, stream>>>(src, dst, n / 4);
  };
  conv1(hgd_w1, w1b, 256 * 1024);
  conv1(hgd_w2, w2b, 1024 * 256);
  conv1(hgf_wm, wmb, 256 * 1024);
  conv1(hgf_wr, wrb, 256 * 1024);
  conv1(hgf_wf, wfb, 1024 * 256);
  conv1(in_w, inwb, 4096 * 1024);
  conv1(xproj_w, xpb, 96 * 2048);
  conv1(dtproj_w, dtpb, 2048 * 64);
  conv1(out_w, owb, 1024 * 2048);

  modcalc_kernel<<<(Bn * 3072) / 4, 256, 0, stream>>>(c, adaln_w, adaln_b, modb);

  dim3 blk(256);
  int gy = (int)(Mc / 128);
  for (int ck = 0; ck < nchunk; ++ck) {
    int b0 = ck * BC;
    const float* xch = x + (size_t)b0 * Ln * Hn;
    float* och = (float*)d_out + (size_t)b0 * Ln * Hn;

    ln_mod_kernel<<<(int)(Mc / 4), blk, 0, stream>>>(xch, modb, x1, b0);
    gemm_k<2><<<dim3(2, gy), blk, 0, stream>>>(x1, w1b, hgd_b1, nullptr, nullptr, nullptr, t1, 256, 1024, 0);
    gemm_k<1><<<dim3(8, gy), blk, 0, stream>>>(t1, w2b, hgd_b2, nullptr, nullptr, nullptr, hd, 1024, 256, 0);
    gemm_k<0><<<dim3(16, gy), blk, 0, stream>>>(hd, inwb, nullptr, nullptr, nullptr, nullptr, xm, 2048, 1024, 0);
    conv_kernel<<<(int)(Mc * 2048 / 256), blk, 0, stream>>>(xm, conv_w, conv_b, xct);
    gemm_k<5><<<dim3(1, gy), blk, 0, stream>>>(xct, xpb, nullptr, nullptr, nullptr, nullptr, dbl, 96, 2048, 0);
    dtslice_kernel<<<(int)(Mc * 64 / 256), blk, 0, stream>>>(dbl, dtb);
    gemm_k<3><<<dim3(16, gy), blk, 0, stream>>>(dtb, dtpb, dt_bias, nullptr, nullptr, nullptr, xm, 2048, 64, 0);
    // chunked parallel scan: dt(xm), xc(xct), B/C(dbl) -> y_raw in place in xm
    scan_part1<<<(int)(BC * 512), blk, 0, stream>>>(xm, xct, dbl, A_log, hq, sd);
    scan_combine<<<(int)(BC * 128), blk, 0, stream>>>(A_log, sd, hq);
    scan_part2<<<(int)(BC * 512), blk, 0, stream>>>(xm, xct, dbl, A_log, Dv, hq, xm);
    // gating: y = silu(hd @ Wz^T) * y_raw (in place)
    gemm_k<7><<<dim3(16, gy), blk, 0, stream>>>(hd, inwb + (size_t)2048 * 1024, nullptr, xm, nullptr, nullptr, xm, 2048, 1024, 0);
    gemm_k<0><<<dim3(8, gy), blk, 0, stream>>>(xm, owb, nullptr, nullptr, nullptr, nullptr, hd, 1024, 2048, 0);
    gemm_k<2><<<dim3(2, gy), blk, 0, stream>>>(hd, wmb, hgf_bm, nullptr, nullptr, nullptr, t1, 256, 1024, 0);
    gemm_k<4><<<dim3(2, gy), blk, 0, stream>>>(x1, wrb, hgf_br, t1, nullptr, nullptr, t1, 256, 1024, 0);
    gemm_k<6><<<dim3(8, gy), blk, 0, stream>>>(t1, wfb, hgf_bf, nullptr, xch, modb, och, 1024, 256, b0);
  }
}